// Round 10
// baseline (217.826 us; speedup 1.0000x reference)
//
#include <hip/hip_runtime.h>

#define FEAT 512
#define F4   128          // float4 per row
#define NSEG 1024
#define CHUNK 1024        // rows per block in fused pass
#define NRG   8           // row-groups in fused pass (1024 threads / 128 lanes)

typedef float f4_t __attribute__((ext_vector_type(4)));

// ---------------- K1: segment boundaries + zero sums ----------------
__global__ void bounds_zero_kernel(const int* __restrict__ seg,
                                   int* __restrict__ starts,
                                   float* __restrict__ sums, int total) {
    int i = blockIdx.x * blockDim.x + threadIdx.x;
    if (sums != nullptr && i < NSEG * FEAT / 2) {
        ((float2*)sums)[i] = make_float2(0.f, 0.f);
    }
    if (i >= total) return;
    int cur = seg[i];
    int prev = (i == 0) ? -1 : seg[i - 1];
    for (int s = prev + 1; s <= cur; ++s) starts[s] = i;
    if (i == total - 1) {
        for (int s = cur + 1; s <= NSEG; ++s) starts[s] = total;
    }
}

// ---------------- K2: fused sum + interior broadcast ----------------
// Block owns CHUNK rows. Per overlapping segment: NT x8 sum -> LDS reduce.
// Interior segments (fully inside the chunk): broadcast mean immediately
// (mixes read+write traffic chip-wide). Boundary segments: atomic flush.
__global__ __launch_bounds__(1024) void fused_sum_bcast_kernel(
        const float* __restrict__ batch,
        const int* __restrict__ seg,
        const int* __restrict__ starts,
        float* __restrict__ sums,
        float* __restrict__ out, int total) {
    const int tid  = threadIdx.x;
    const int lane = tid & (F4 - 1);   // f4 column 0..127
    const int rg   = tid >> 7;         // row-group 0..7
    const int r0   = blockIdx.x * CHUNK;
    if (r0 >= total) return;
    const int r1   = min(r0 + CHUNK, total);

    const int s0 = seg[r0];
    const int s1 = seg[r1 - 1];

    const f4_t* b4 = (const f4_t*)batch;
    f4_t* o4 = (f4_t*)out;
    __shared__ f4_t red[NRG][F4];

    for (int s = s0; s <= s1; ++s) {
        const int sa = starts[s];
        const int sb = starts[s + 1];
        const int a = max(sa, r0);     // block-uniform
        const int b = min(sb, r1);     // block-uniform
        if (a >= b) continue;          // empty segment (uniform skip)
        const bool interior = (sa >= r0) && (sb <= r1);  // block-uniform

        f4_t a0 = (f4_t)(0.f);
        f4_t a1 = (f4_t)(0.f);
        int r = a + rg;
        for (; r + 7 * NRG < b; r += 8 * NRG) {
            const f4_t* p = b4 + (size_t)r * F4 + lane;
            f4_t v0 = __builtin_nontemporal_load(p + 0 * NRG * F4);
            f4_t v1 = __builtin_nontemporal_load(p + 1 * NRG * F4);
            f4_t v2 = __builtin_nontemporal_load(p + 2 * NRG * F4);
            f4_t v3 = __builtin_nontemporal_load(p + 3 * NRG * F4);
            f4_t v4 = __builtin_nontemporal_load(p + 4 * NRG * F4);
            f4_t v5 = __builtin_nontemporal_load(p + 5 * NRG * F4);
            f4_t v6 = __builtin_nontemporal_load(p + 6 * NRG * F4);
            f4_t v7 = __builtin_nontemporal_load(p + 7 * NRG * F4);
            a0 += v0; a1 += v1;
            a0 += v2; a1 += v3;
            a0 += v4; a1 += v5;
            a0 += v6; a1 += v7;
        }
        for (; r < b; r += NRG) {
            a0 += __builtin_nontemporal_load(b4 + (size_t)r * F4 + lane);
        }
        a0 += a1;

        red[rg][lane] = a0;
        __syncthreads();
        if (rg == 0) {
            f4_t t = red[0][lane];
            #pragma unroll
            for (int g = 1; g < NRG; ++g) t += red[g][lane];
            if (interior) {
                const float inv = 1.0f / (float)(sb - sa);
                red[0][lane] = t * inv;
            } else {
                float* dst = sums + (size_t)s * FEAT + lane * 4;
                atomicAdd(dst + 0, t.x);
                atomicAdd(dst + 1, t.y);
                atomicAdd(dst + 2, t.z);
                atomicAdd(dst + 3, t.w);
            }
        }
        __syncthreads();
        if (interior) {
            const f4_t mean = red[0][lane];
            __syncthreads();   // everyone has mean in reg before red is reused
            int r2 = a + rg;
            for (; r2 + 7 * NRG < b; r2 += 8 * NRG) {
                f4_t* q = o4 + (size_t)r2 * F4 + lane;
                __builtin_nontemporal_store(mean, q + 0 * NRG * F4);
                __builtin_nontemporal_store(mean, q + 1 * NRG * F4);
                __builtin_nontemporal_store(mean, q + 2 * NRG * F4);
                __builtin_nontemporal_store(mean, q + 3 * NRG * F4);
                __builtin_nontemporal_store(mean, q + 4 * NRG * F4);
                __builtin_nontemporal_store(mean, q + 5 * NRG * F4);
                __builtin_nontemporal_store(mean, q + 6 * NRG * F4);
                __builtin_nontemporal_store(mean, q + 7 * NRG * F4);
            }
            for (; r2 < b; r2 += NRG) {
                __builtin_nontemporal_store(mean, o4 + (size_t)r2 * F4 + lane);
            }
        }
    }
}

// ---------------- K3: boundary-segment broadcast (~25% of rows) ----------------
// One block per segment; skips empty and interior segments.
__global__ __launch_bounds__(256) void boundary_bcast_kernel(
        const int* __restrict__ starts,
        const float* __restrict__ sums,
        float* __restrict__ out, int total) {
    const int s  = blockIdx.x;
    const int sa = starts[s];
    const int sb = starts[s + 1];
    if (sa >= sb) return;
    if (sa / CHUNK == (sb - 1) / CHUNK) return;   // interior: K2 wrote it
    const int lane = threadIdx.x & (F4 - 1);
    const int rg   = threadIdx.x >> 7;            // 0..1
    const float inv = 1.0f / (float)(sb - sa);
    const f4_t mean = ((const f4_t*)sums)[(size_t)s * F4 + lane] * inv;
    f4_t* o4 = (f4_t*)out;
    int r = sa + rg;
    for (; r + 14 < sb; r += 16) {
        f4_t* q = o4 + (size_t)r * F4 + lane;
        __builtin_nontemporal_store(mean, q + 0 * 2 * F4);
        __builtin_nontemporal_store(mean, q + 1 * 2 * F4);
        __builtin_nontemporal_store(mean, q + 2 * 2 * F4);
        __builtin_nontemporal_store(mean, q + 3 * 2 * F4);
        __builtin_nontemporal_store(mean, q + 4 * 2 * F4);
        __builtin_nontemporal_store(mean, q + 5 * 2 * F4);
        __builtin_nontemporal_store(mean, q + 6 * 2 * F4);
        __builtin_nontemporal_store(mean, q + 7 * 2 * F4);
    }
    for (; r < sb; r += 2) {
        __builtin_nontemporal_store(mean, o4 + (size_t)r * F4 + lane);
    }
}

// ---------------- Fallback: R5 fused kernel (needs only ~4KB ws) --------------
__global__ __launch_bounds__(512) void seg_mean_fused_kernel(
        const float* __restrict__ batch,
        const int* __restrict__ starts,
        float* __restrict__ out) {
    const int s      = blockIdx.x;
    const int tid    = threadIdx.x;
    const int lane_f = tid & (F4 - 1);
    const int rgrp   = tid >> 7;

    const int start = starts[s];
    const int end   = starts[s + 1];
    const int count = end - start;

    const f4_t* b4 = (const f4_t*)batch;
    f4_t a0 = (f4_t)(0.f);
    f4_t a1 = (f4_t)(0.f);

    int r = start + rgrp;
    for (; r + 28 < end; r += 32) {
        const f4_t* p = b4 + (size_t)r * F4 + lane_f;
        f4_t v0 = __builtin_nontemporal_load(p + 0 * 4 * F4);
        f4_t v1 = __builtin_nontemporal_load(p + 1 * 4 * F4);
        f4_t v2 = __builtin_nontemporal_load(p + 2 * 4 * F4);
        f4_t v3 = __builtin_nontemporal_load(p + 3 * 4 * F4);
        f4_t v4 = __builtin_nontemporal_load(p + 4 * 4 * F4);
        f4_t v5 = __builtin_nontemporal_load(p + 5 * 4 * F4);
        f4_t v6 = __builtin_nontemporal_load(p + 6 * 4 * F4);
        f4_t v7 = __builtin_nontemporal_load(p + 7 * 4 * F4);
        a0 += v0; a1 += v1;
        a0 += v2; a1 += v3;
        a0 += v4; a1 += v5;
        a0 += v6; a1 += v7;
    }
    for (; r < end; r += 4) {
        a0 += __builtin_nontemporal_load(b4 + (size_t)r * F4 + lane_f);
    }
    a0 += a1;

    __shared__ f4_t red[4][F4];
    red[rgrp][lane_f] = a0;
    __syncthreads();

    if (rgrp == 0) {
        f4_t p0 = red[0][lane_f];
        f4_t p1 = red[1][lane_f];
        f4_t p2 = red[2][lane_f];
        f4_t p3 = red[3][lane_f];
        const float inv = 1.0f / (float)(count > 0 ? count : 1);
        red[0][lane_f] = (p0 + p1 + p2 + p3) * inv;
    }
    __syncthreads();

    const f4_t mean = red[0][lane_f];
    f4_t* o4 = (f4_t*)out;

    r = start + rgrp;
    for (; r + 28 < end; r += 32) {
        f4_t* q = o4 + (size_t)r * F4 + lane_f;
        __builtin_nontemporal_store(mean, q + 0 * 4 * F4);
        __builtin_nontemporal_store(mean, q + 1 * 4 * F4);
        __builtin_nontemporal_store(mean, q + 2 * 4 * F4);
        __builtin_nontemporal_store(mean, q + 3 * 4 * F4);
        __builtin_nontemporal_store(mean, q + 4 * 4 * F4);
        __builtin_nontemporal_store(mean, q + 5 * 4 * F4);
        __builtin_nontemporal_store(mean, q + 6 * 4 * F4);
        __builtin_nontemporal_store(mean, q + 7 * 4 * F4);
    }
    for (; r < end; r += 4) {
        __builtin_nontemporal_store(mean, o4 + (size_t)r * F4 + lane_f);
    }
}

extern "C" void kernel_launch(void* const* d_in, const int* in_sizes, int n_in,
                              void* d_out, int out_size, void* d_ws, size_t ws_size,
                              hipStream_t stream) {
    const float* batch = (const float*)d_in[0];
    const int*   seg   = (const int*)d_in[1];
    float*       out   = (float*)d_out;
    const int total    = in_sizes[1];

    // ws layout: [sums: 2MB][starts: (NSEG+1)*4]
    const size_t sums_bytes = (size_t)NSEG * FEAT * sizeof(float);
    const size_t need       = sums_bytes + (NSEG + 1) * sizeof(int);

    const int nblk256 = (total + 255) / 256;

    if (ws_size >= need) {
        float* sums   = (float*)d_ws;
        int*   starts = (int*)((char*)d_ws + sums_bytes);

        bounds_zero_kernel<<<nblk256, 256, 0, stream>>>(seg, starts, sums, total);
        const int nchunks = (total + CHUNK - 1) / CHUNK;
        fused_sum_bcast_kernel<<<nchunks, 1024, 0, stream>>>(batch, seg, starts, sums, out, total);
        boundary_bcast_kernel<<<NSEG, 256, 0, stream>>>(starts, sums, out, total);
    } else {
        int* starts = (int*)d_ws;
        bounds_zero_kernel<<<nblk256, 256, 0, stream>>>(seg, starts, nullptr, total);
        seg_mean_fused_kernel<<<NSEG, 512, 0, stream>>>(batch, starts, out);
    }
}